// Round 11
// baseline (329.208 us; speedup 1.0000x reference)
//
#include <hip/hip_runtime.h>
#include <cmath>

#define NB 256   // batch
#define NT 512   // seq len
#define ND 50    // emb dim
#define NH 50    // hidden
#define NC 5     // classes

typedef float f32x4 __attribute__((ext_vector_type(4)));
typedef float f32x2 __attribute__((ext_vector_type(2)));

__device__ __forceinline__ float rcpf(float x) { return __builtin_amdgcn_rcpf(x); }
// asm loads: results are NOT rematerializable -> allocator must keep them in VGPRs
// (but CAN spill them -- round 10 lesson: must also pin the VGPR budget via waves_per_eu).
// ONLY ever called on 16B-aligned addresses (52-float padded rows from k0 / xp quads).
__device__ __forceinline__ void gload4(f32x4& d, const float* p) {
    asm volatile("global_load_dwordx4 %0, %1, off" : "=v"(d) : "v"(p));
}

// ---------------- K0: repack weights into padded [200][52] rows (16B-aligned) ------------
__global__ __launch_bounds__(256)
void k0_prep(const float* __restrict__ W_hh, const float* __restrict__ W_ih,
             float* __restrict__ wsWih, float* __restrict__ wsWhh)
{
    int idx = blockIdx.x * 256 + threadIdx.x;
    if (idx < 200 * 52) {
        int d = idx / 52, c = idx - (idx / 52) * 52;
        wsWih[idx] = (c < ND) ? W_ih[d * ND + c] : 0.f;
    } else if (idx < 2 * 200 * 52) {
        int j = idx - 200 * 52;
        int d = j / 52, c = j - (j / 52) * 52;
        wsWhh[j] = (c < NH) ? W_hh[d * NH + c] : 0.f;
    }
}

#define DECLROW(P) f32x4 P##_0{},P##_1{},P##_2{},P##_3{},P##_4{},P##_5{},P##_6{},P##_7{}, \
                         P##_8{},P##_9{},P##_10{},P##_11{},P##_12{};
#define LOADROW(P,B) { const float* b_=(B); \
    gload4(P##_0,b_+0);  gload4(P##_1,b_+4);  gload4(P##_2,b_+8);  gload4(P##_3,b_+12); \
    gload4(P##_4,b_+16); gload4(P##_5,b_+20); gload4(P##_6,b_+24); gload4(P##_7,b_+28); \
    gload4(P##_8,b_+32); gload4(P##_9,b_+36); gload4(P##_10,b_+40); gload4(P##_11,b_+44); \
    gload4(P##_12,b_+48); }

// k1 dot: gold order (13 tuples over the zero-padded row; pads are exact no-ops)
#define DOTI(J, HP) { f32x4 h4 = (HP)[J];                          \
    a0 = fmaf(h4.x, w##J.x, a0); a1 = fmaf(h4.y, w##J.y, a1);     \
    a2 = fmaf(h4.z, w##J.z, a2); a3 = fmaf(h4.w, w##J.w, a3); }
#define DOTI13(HP) DOTI(0,HP) DOTI(1,HP) DOTI(2,HP) DOTI(3,HP) DOTI(4,HP) DOTI(5,HP) \
    DOTI(6,HP) DOTI(7,HP) DOTI(8,HP) DOTI(9,HP) DOTI(10,HP) DOTI(11,HP) DOTI(12,HP)

// ---------------- K1: xp[b,t,4u+g] = W_ih[g*50+u] . emb[x[b,t]] + b_ih + b_hh ------------
// (verbatim proven structure from rounds 5/7/10)
__global__ __launch_bounds__(256)
void k1_xproj(const int* __restrict__ x, const int* __restrict__ lengths,
              const float* __restrict__ emb_table,
              const float* __restrict__ wsWih, const float* __restrict__ b_ih,
              const float* __restrict__ b_hh,
              float* __restrict__ xp, int t0, int t1, int tiles, int tcAlloc)
{
    const int b    = blockIdx.x / tiles;
    const int tile = blockIdx.x % tiles;
    const int rt0  = t0 + tile * 64;
    if (rt0 >= t1) return;
    if (rt0 >= lengths[b]) return;            // rows past length are never consumed
    const int nrows = min(64, t1 - rt0);

    __shared__ int xv[64];
    __shared__ __align__(16) float eL[64][52];

    const int tid = threadIdx.x;

    float bsum = 0.f;
    const float* wrow = wsWih + tid * 52;
    f32x4 w0{},w1{},w2{},w3{},w4{},w5{},w6{},w7{},w8{},w9{},w10{},w11{},w12{};
    gload4(w0,wrow+0); gload4(w1,wrow+4); gload4(w2,wrow+8); gload4(w3,wrow+12);
    gload4(w4,wrow+16); gload4(w5,wrow+20); gload4(w6,wrow+24); gload4(w7,wrow+28);
    gload4(w8,wrow+32); gload4(w9,wrow+36); gload4(w10,wrow+40); gload4(w11,wrow+44);
    gload4(w12,wrow+48);
    if (tid < 200) bsum = b_ih[tid] + b_hh[tid];
    if (tid < nrows) xv[tid] = x[(size_t)b * NT + rt0 + tid];
    __syncthreads();
    for (int idx = tid; idx < nrows * 52; idx += 256) {
        int row = idx / 52, col = idx - row * 52;
        eL[row][col] = (col < ND) ? emb_table[(size_t)xv[row] * ND + col] : 0.f;
    }
    asm volatile("s_waitcnt vmcnt(0)" ::: "memory");  // weights resident
    __builtin_amdgcn_sched_barrier(0);
    __syncthreads();
    if (tid < 200) {
        const int wr = 4 * (tid % NH) + (tid / NH);   // quad-permuted position
        float* xpb = xp + ((size_t)b * tcAlloc + (rt0 - t0)) * 200 + wr;
        for (int row = 0; row < nrows; ++row) {
            const f32x4* ep = (const f32x4*)&eL[row][0];
            float a0 = bsum, a1 = 0.f, a2 = 0.f, a3 = 0.f;
            DOTI13(ep)
            xpb[(size_t)row * 200] = (a0 + a1) + (a2 + a3);
        }
    }
}

// ---------------- K2: single-wave scan — ZERO barriers, lane k owns unit k ---------------
// gate dot: gold order — a0/a1 (j%4==0/1) in A01, a2/a3 (j%4==2/3) in A23,
// tails h48->a2, h49->a3, combine (a0+a1)+(a2+a3). Bitwise == rounds 1-3/5/7/10.
#define CP(Q,M) A01 = __builtin_elementwise_fma(H##M.xy, CW##Q##_##M.xy, A01); \
                A23 = __builtin_elementwise_fma(H##M.zw, CW##Q##_##M.zw, A23);
#define CDOT(Q,SEED,OUT) { f32x2 A01 = {(SEED), 0.f}, A23 = {0.f, 0.f}; \
    CP(Q,0) CP(Q,1) CP(Q,2) CP(Q,3) CP(Q,4) CP(Q,5) CP(Q,6) CP(Q,7) CP(Q,8) CP(Q,9) CP(Q,10) CP(Q,11) \
    A23 = __builtin_elementwise_fma(HT, CW##Q##_12.xy, A23); \
    OUT = (A01.x + A01.y) + (A23.x + A23.y); }

#define SSTEP(XQ, S) {                                                        \
    const f32x4* hq = (const f32x4*)hbuf;                                     \
    f32x4 H0=hq[0],H1=hq[1],H2=hq[2],H3=hq[3],H4=hq[4],H5=hq[5],              \
          H6=hq[6],H7=hq[7],H8=hq[8],H9=hq[9],H10=hq[10],H11=hq[11];          \
    f32x2 HT = *(const f32x2*)&hbuf[48];                                      \
    float g0,g1,g2,g3;                                                        \
    CDOT(0, XQ.x, g0)                                                         \
    CDOT(1, XQ.y, g1)                                                         \
    CDOT(2, XQ.z, g2)                                                         \
    CDOT(3, XQ.w, g3)                                                         \
    { int sn_ = (S) + 4; if (sn_ > nsteps - 1) sn_ = nsteps - 1;              \
      XQ = *(const f32x4*)&xpb[(size_t)sn_ * 200]; }                          \
    float i_ = rcpf(1.f + __expf(-g0));                                       \
    float f_ = rcpf(1.f + __expf(-g1));                                       \
    float gt = fmaf(rcpf(1.f + __expf(-2.f * g2)), 2.f, -1.f);                \
    float o_ = rcpf(1.f + __expf(-g3));                                       \
    cst = fmaf(f_, cst, i_ * gt);                                             \
    float th = fmaf(rcpf(1.f + __expf(-2.f * cst)), 2.f, -1.f);               \
    float hv = o_ * th;                                                       \
    hfin = hv;                                                                \
    hkeep = (t0 + (S) == lastidx) ? hv : hkeep;                               \
    if (kln < NH) hbuf[kln] = hv;                                             \
    asm volatile("" ::: "memory");  /* no hoisting next step's reads above */ \
}

__global__ __launch_bounds__(64)
__attribute__((amdgpu_waves_per_eu(1, 1)))   // pin 1 wave/EU -> full 512-VGPR budget, NO spill
void k2_scan(const int* __restrict__ lengths, const float* __restrict__ wsWhh,
             const float* __restrict__ xp,
             float* __restrict__ stH, float* __restrict__ stC, float* __restrict__ lastH,
             int t0, int t1, int tcAlloc)
{
    const int b = blockIdx.x, kln = threadIdx.x;
    const int kc = (kln < NH) ? kln : NH - 1;     // clamped unit (lanes 50-63 shadow 49)
    __shared__ __align__(16) float hbuf[64];

    const int lastidx = min(lengths[b], NT) - 1;
    const int nsteps  = t1 - t0;

    float cst = 0.f;
    if (kln < NH && t0 != 0) cst = stC[b * NH + kln];
    hbuf[kln] = (t0 == 0 || kln >= NH) ? 0.f : stH[b * NH + kln];
    asm volatile("" ::: "memory");

    // weights: 4 gate rows x 13 aligned dwordx4, asm-pinned (208 VGPRs; fits 512 budget)
    DECLROW(CW0) DECLROW(CW1) DECLROW(CW2) DECLROW(CW3)
    LOADROW(CW0, wsWhh + (0*NH + kc)*52)
    LOADROW(CW1, wsWhh + (1*NH + kc)*52)
    LOADROW(CW2, wsWhh + (2*NH + kc)*52)
    LOADROW(CW3, wsWhh + (3*NH + kc)*52)
    asm volatile("s_waitcnt vmcnt(0)" ::: "memory");
    __builtin_amdgcn_sched_barrier(0);

    // xp: 4-deep compiler-visible rotation (no barriers exist to drain it)
    const float* xpb = xp + (size_t)b * tcAlloc * 200 + 4 * kc;
    f32x4 xq0 = *(const f32x4*)&xpb[0];
    f32x4 xq1 = *(const f32x4*)&xpb[200];
    f32x4 xq2 = *(const f32x4*)&xpb[400];
    f32x4 xq3 = *(const f32x4*)&xpb[600];
    float hkeep = 0.f, hfin = 0.f;

    for (int s4 = 0; s4 < nsteps; s4 += 4) {
        SSTEP(xq0, s4 + 0)
        SSTEP(xq1, s4 + 1)
        SSTEP(xq2, s4 + 2)
        SSTEP(xq3, s4 + 3)
    }

    if (kln < NH) {
        stH[b * NH + kln] = hfin;
        stC[b * NH + kln] = cst;
        if (lastidx >= t0 && lastidx < t1) lastH[b * NH + kln] = hkeep;
    }
}

// ---------------- K3: pooling + concat + linear (unchanged — proven) ---------------------
__global__ __launch_bounds__(256)
void k3_final(const int* __restrict__ x, const int* __restrict__ lengths,
              const float* __restrict__ emb_table,
              const float* __restrict__ W_lin, const float* __restrict__ b_lin,
              const float* __restrict__ lastH, float* __restrict__ out)
{
    const int b = blockIdx.x, tid = threadIdx.x;
    __shared__ int xv[NT];
    __shared__ float ps[5][52], pm[5][52];
    __shared__ float rep[160];

    for (int i = tid; i < NT; i += 256) xv[i] = x[(size_t)b * NT + i];
    __syncthreads();
    const int g = tid / ND, d = tid - g * ND;
    if (tid < 250) {
        float s = 0.f, m = -INFINITY;
        #pragma unroll 4
        for (int t = g; t < NT; t += 5) {
            float e = emb_table[(size_t)xv[t] * ND + d];
            s += e; m = fmaxf(m, e);
        }
        ps[g][d] = s; pm[g][d] = m;
    }
    __syncthreads();
    if (tid < NH) {
        float s = ps[0][tid] + ps[1][tid] + ps[2][tid] + ps[3][tid] + ps[4][tid];
        float m = fmaxf(fmaxf(fmaxf(pm[0][tid], pm[1][tid]), fmaxf(pm[2][tid], pm[3][tid])), pm[4][tid]);
        rep[tid]          = lastH[b * NH + tid];
        rep[NH + tid]     = s / (float)lengths[b];
        rep[2 * NH + tid] = m;
    }
    __syncthreads();
    if (tid < NC) {
        float acc = b_lin[tid];
        #pragma unroll 5
        for (int j = 0; j < 3 * NH; ++j)
            acc = fmaf(rep[j], W_lin[tid * 3 * NH + j], acc);
        out[(size_t)b * NC + tid] = acc;
    }
}

extern "C" void kernel_launch(void* const* d_in, const int* in_sizes, int n_in,
                              void* d_out, int out_size, void* d_ws, size_t ws_size,
                              hipStream_t stream) {
    const int*   x     = (const int*)d_in[0];
    const int*   len   = (const int*)d_in[1];
    const float* emb   = (const float*)d_in[3];
    const float* W_ih  = (const float*)d_in[4];
    const float* W_hh  = (const float*)d_in[5];
    const float* b_ih  = (const float*)d_in[6];
    const float* b_hh  = (const float*)d_in[7];
    const float* W_lin = (const float*)d_in[8];
    const float* b_lin = (const float*)d_in[9];
    float* outp = (float*)d_out;

    // ws: [stH][stC][lastH] | @160KB: wsWih[200*52], wsWhh[200*52] | @256KB: xp (+8KB slack)
    float* stH   = (float*)d_ws;
    float* stC   = stH + NB * NH;
    float* lastH = stC + NB * NH;
    float* wsWih = (float*)((char*)d_ws + 160 * 1024);
    float* wsWhh = wsWih + 200 * 52;
    const size_t xpOff = 256 * 1024;
    float* xp = (float*)((char*)d_ws + xpOff);

    size_t avail = (ws_size > xpOff + 8192) ? ws_size - xpOff - 8192 : 0;
    int tc = (int)(avail / ((size_t)NB * 200 * sizeof(float)));
    tc &= ~3;                 // chunks are multiples of 4 (NT=512 -> every chunk too)
    if (tc > NT) tc = NT;
    if (tc < 4)  tc = 4;

    hipLaunchKernelGGL(k0_prep, dim3(82), dim3(256), 0, stream, W_hh, W_ih, wsWih, wsWhh);

    for (int t0 = 0; t0 < NT; t0 += tc) {
        const int t1 = min(NT, t0 + tc);
        const int tiles = (t1 - t0 + 63) / 64;
        hipLaunchKernelGGL(k1_xproj, dim3(NB * tiles), dim3(256), 0, stream,
                           x, len, emb, wsWih, b_ih, b_hh, xp, t0, t1, tiles, tc);
        hipLaunchKernelGGL(k2_scan, dim3(NB), dim3(64), 0, stream,
                           len, wsWhh, xp, stH, stC, lastH, t0, t1, tc);
    }
    hipLaunchKernelGGL(k3_final, dim3(NB), dim3(256), 0, stream,
                       x, len, emb, W_lin, b_lin, lastH, outp);
}

// Round 12
// 325.912 us; speedup vs baseline: 1.0101x; 1.0101x over previous
//
#include <hip/hip_runtime.h>
#include <cmath>

#define NB 256   // batch
#define NT 512   // seq len
#define ND 50    // emb dim
#define NH 50    // hidden
#define NC 5     // classes

typedef float f32x4 __attribute__((ext_vector_type(4)));
typedef float f32x2 __attribute__((ext_vector_type(2)));

__device__ __forceinline__ float rcpf(float x) { return __builtin_amdgcn_rcpf(x); }
// readlane: uniform result -> compiler allocates SGPR; lane index compile-time const
__device__ __forceinline__ float rdl(float v, int l) {
    return __int_as_float(__builtin_amdgcn_readlane(__float_as_int(v), l));
}
// asm loads: results are NOT rematerializable -> allocator must keep them resident.
// ONLY ever called on 16B-aligned addresses (52-float padded rows from k0).
__device__ __forceinline__ void gload4(f32x4& d, const float* p) {
    asm volatile("global_load_dwordx4 %0, %1, off" : "=v"(d) : "v"(p));
}

// ---------------- K0: repack weights into padded [200][52] rows (16B-aligned) ------------
__global__ __launch_bounds__(256)
void k0_prep(const float* __restrict__ W_hh, const float* __restrict__ W_ih,
             float* __restrict__ wsWih, float* __restrict__ wsWhh)
{
    int idx = blockIdx.x * 256 + threadIdx.x;
    if (idx < 200 * 52) {
        int d = idx / 52, c = idx - (idx / 52) * 52;
        wsWih[idx] = (c < ND) ? W_ih[d * ND + c] : 0.f;
    } else if (idx < 2 * 200 * 52) {
        int j = idx - 200 * 52;
        int d = j / 52, c = j - (j / 52) * 52;
        wsWhh[j] = (c < NH) ? W_hh[d * NH + c] : 0.f;
    }
}

#define DECLROW(P) f32x4 P##_0{},P##_1{},P##_2{},P##_3{},P##_4{},P##_5{},P##_6{},P##_7{}, \
                         P##_8{},P##_9{},P##_10{},P##_11{},P##_12{};
#define LOADROW(P,B) { const float* b_=(B); \
    gload4(P##_0,b_+0);  gload4(P##_1,b_+4);  gload4(P##_2,b_+8);  gload4(P##_3,b_+12); \
    gload4(P##_4,b_+16); gload4(P##_5,b_+20); gload4(P##_6,b_+24); gload4(P##_7,b_+28); \
    gload4(P##_8,b_+32); gload4(P##_9,b_+36); gload4(P##_10,b_+40); gload4(P##_11,b_+44); \
    gload4(P##_12,b_+48); }

// k1 dot: gold order (13 tuples over the zero-padded row; pads are exact no-ops)
#define DOTI(J, HP) { f32x4 h4 = (HP)[J];                          \
    a0 = fmaf(h4.x, w##J.x, a0); a1 = fmaf(h4.y, w##J.y, a1);     \
    a2 = fmaf(h4.z, w##J.z, a2); a3 = fmaf(h4.w, w##J.w, a3); }
#define DOTI13(HP) DOTI(0,HP) DOTI(1,HP) DOTI(2,HP) DOTI(3,HP) DOTI(4,HP) DOTI(5,HP) \
    DOTI(6,HP) DOTI(7,HP) DOTI(8,HP) DOTI(9,HP) DOTI(10,HP) DOTI(11,HP) DOTI(12,HP)

// ---------------- K1: xp[b,t,4u+g] = W_ih[g*50+u] . emb[x[b,t]] + b_ih + b_hh ------------
// (verbatim proven structure from rounds 5/7/10/11)
__global__ __launch_bounds__(256)
void k1_xproj(const int* __restrict__ x, const int* __restrict__ lengths,
              const float* __restrict__ emb_table,
              const float* __restrict__ wsWih, const float* __restrict__ b_ih,
              const float* __restrict__ b_hh,
              float* __restrict__ xp, int t0, int t1, int tiles, int tcAlloc)
{
    const int b    = blockIdx.x / tiles;
    const int tile = blockIdx.x % tiles;
    const int rt0  = t0 + tile * 64;
    if (rt0 >= t1) return;
    if (rt0 >= lengths[b]) return;            // rows past length are never consumed
    const int nrows = min(64, t1 - rt0);

    __shared__ int xv[64];
    __shared__ __align__(16) float eL[64][52];

    const int tid = threadIdx.x;

    float bsum = 0.f;
    const float* wrow = wsWih + tid * 52;
    f32x4 w0{},w1{},w2{},w3{},w4{},w5{},w6{},w7{},w8{},w9{},w10{},w11{},w12{};
    gload4(w0,wrow+0); gload4(w1,wrow+4); gload4(w2,wrow+8); gload4(w3,wrow+12);
    gload4(w4,wrow+16); gload4(w5,wrow+20); gload4(w6,wrow+24); gload4(w7,wrow+28);
    gload4(w8,wrow+32); gload4(w9,wrow+36); gload4(w10,wrow+40); gload4(w11,wrow+44);
    gload4(w12,wrow+48);
    if (tid < 200) bsum = b_ih[tid] + b_hh[tid];
    if (tid < nrows) xv[tid] = x[(size_t)b * NT + rt0 + tid];
    __syncthreads();
    for (int idx = tid; idx < nrows * 52; idx += 256) {
        int row = idx / 52, col = idx - row * 52;
        eL[row][col] = (col < ND) ? emb_table[(size_t)xv[row] * ND + col] : 0.f;
    }
    asm volatile("s_waitcnt vmcnt(0)" ::: "memory");  // weights resident
    __builtin_amdgcn_sched_barrier(0);
    __syncthreads();
    if (tid < 200) {
        const int wr = 4 * (tid % NH) + (tid / NH);   // quad-permuted position
        float* xpb = xp + ((size_t)b * tcAlloc + (rt0 - t0)) * 200 + wr;
        for (int row = 0; row < nrows; ++row) {
            const f32x4* ep = (const f32x4*)&eL[row][0];
            float a0 = bsum, a1 = 0.f, a2 = 0.f, a3 = 0.f;
            DOTI13(ep)
            xpb[(size_t)row * 200] = (a0 + a1) + (a2 + a3);
        }
    }
}

// ---------------- K2: single-wave scan — NO LDS, h broadcast via readlane->SGPR pairs ----
// gate dot, bitwise-gold: A01=(a0,a1) over j%4∈{0,1}, A23=(a2,a3) over j%4∈{2,3},
// tails h48->a2, h49->a3, combine (a0+a1)+(a2+a3). hp_m=(h_{2m},h_{2m+1}) is wave-uniform.
#define FMA2(H,W,A) __builtin_elementwise_fma((H),(W),(A))
#define CDOT(Q,SEED,OUT) { f32x2 A01 = {(SEED), 0.f}, A23 = {0.f, 0.f};       \
    A01=FMA2(hp0 ,CW##Q##_0.xy ,A01); A23=FMA2(hp1 ,CW##Q##_0.zw ,A23);       \
    A01=FMA2(hp2 ,CW##Q##_1.xy ,A01); A23=FMA2(hp3 ,CW##Q##_1.zw ,A23);       \
    A01=FMA2(hp4 ,CW##Q##_2.xy ,A01); A23=FMA2(hp5 ,CW##Q##_2.zw ,A23);       \
    A01=FMA2(hp6 ,CW##Q##_3.xy ,A01); A23=FMA2(hp7 ,CW##Q##_3.zw ,A23);       \
    A01=FMA2(hp8 ,CW##Q##_4.xy ,A01); A23=FMA2(hp9 ,CW##Q##_4.zw ,A23);       \
    A01=FMA2(hp10,CW##Q##_5.xy ,A01); A23=FMA2(hp11,CW##Q##_5.zw ,A23);       \
    A01=FMA2(hp12,CW##Q##_6.xy ,A01); A23=FMA2(hp13,CW##Q##_6.zw ,A23);       \
    A01=FMA2(hp14,CW##Q##_7.xy ,A01); A23=FMA2(hp15,CW##Q##_7.zw ,A23);       \
    A01=FMA2(hp16,CW##Q##_8.xy ,A01); A23=FMA2(hp17,CW##Q##_8.zw ,A23);       \
    A01=FMA2(hp18,CW##Q##_9.xy ,A01); A23=FMA2(hp19,CW##Q##_9.zw ,A23);       \
    A01=FMA2(hp20,CW##Q##_10.xy,A01); A23=FMA2(hp21,CW##Q##_10.zw,A23);       \
    A01=FMA2(hp22,CW##Q##_11.xy,A01); A23=FMA2(hp23,CW##Q##_11.zw,A23);       \
    A23=FMA2(hp24,CW##Q##_12.xy,A23);                                         \
    OUT = (A01.x + A01.y) + (A23.x + A23.y); }

#define SSTEP(XQ, S) {                                                        \
    f32x2 hp0 ={rdl(hv,0 ),rdl(hv,1 )}, hp1 ={rdl(hv,2 ),rdl(hv,3 )};         \
    f32x2 hp2 ={rdl(hv,4 ),rdl(hv,5 )}, hp3 ={rdl(hv,6 ),rdl(hv,7 )};         \
    f32x2 hp4 ={rdl(hv,8 ),rdl(hv,9 )}, hp5 ={rdl(hv,10),rdl(hv,11)};         \
    f32x2 hp6 ={rdl(hv,12),rdl(hv,13)}, hp7 ={rdl(hv,14),rdl(hv,15)};         \
    f32x2 hp8 ={rdl(hv,16),rdl(hv,17)}, hp9 ={rdl(hv,18),rdl(hv,19)};         \
    f32x2 hp10={rdl(hv,20),rdl(hv,21)}, hp11={rdl(hv,22),rdl(hv,23)};         \
    f32x2 hp12={rdl(hv,24),rdl(hv,25)}, hp13={rdl(hv,26),rdl(hv,27)};         \
    f32x2 hp14={rdl(hv,28),rdl(hv,29)}, hp15={rdl(hv,30),rdl(hv,31)};         \
    f32x2 hp16={rdl(hv,32),rdl(hv,33)}, hp17={rdl(hv,34),rdl(hv,35)};         \
    f32x2 hp18={rdl(hv,36),rdl(hv,37)}, hp19={rdl(hv,38),rdl(hv,39)};         \
    f32x2 hp20={rdl(hv,40),rdl(hv,41)}, hp21={rdl(hv,42),rdl(hv,43)};         \
    f32x2 hp22={rdl(hv,44),rdl(hv,45)}, hp23={rdl(hv,46),rdl(hv,47)};         \
    f32x2 hp24={rdl(hv,48),rdl(hv,49)};                                       \
    float g0,g1,g2,g3;                                                        \
    CDOT(0, XQ.x, g0)                                                         \
    CDOT(1, XQ.y, g1)                                                         \
    CDOT(2, XQ.z, g2)                                                         \
    CDOT(3, XQ.w, g3)                                                         \
    { int sn_ = (S) + 4; if (sn_ > nsteps - 1) sn_ = nsteps - 1;              \
      XQ = *(const f32x4*)&xpb[(size_t)sn_ * 200]; }                          \
    float i_ = rcpf(1.f + __expf(-g0));                                       \
    float f_ = rcpf(1.f + __expf(-g1));                                       \
    float gt = fmaf(rcpf(1.f + __expf(-2.f * g2)), 2.f, -1.f);                \
    float o_ = rcpf(1.f + __expf(-g3));                                       \
    cst = fmaf(f_, cst, i_ * gt);                                             \
    float th = fmaf(rcpf(1.f + __expf(-2.f * cst)), 2.f, -1.f);               \
    hv = o_ * th;                                                             \
    hkeep = (t0 + (S) == lastidx) ? hv : hkeep;                               \
}

__global__ __launch_bounds__(64)
__attribute__((amdgpu_waves_per_eu(1, 1)))   // 1 wave/EU: full register budget, no spill
void k2_scan(const int* __restrict__ lengths, const float* __restrict__ wsWhh,
             const float* __restrict__ xp,
             float* __restrict__ stH, float* __restrict__ stC, float* __restrict__ lastH,
             int t0, int t1, int tcAlloc)
{
    const int b = blockIdx.x, kln = threadIdx.x;
    const int kc = (kln < NH) ? kln : NH - 1;     // clamped unit (lanes 50-63 shadow 49)

    const int lastidx = min(lengths[b], NT) - 1;
    const int nsteps  = t1 - t0;

    // per-lane recurrent state (lanes 50-63 compute harmless duplicates of unit 49)
    float hv  = (t0 == 0) ? 0.f : stH[b * NH + kc];
    float cst = (t0 == 0) ? 0.f : stC[b * NH + kc];

    // weights: 4 gate rows x 13 aligned dwordx4 = 208 VGPRs (fits: no H regs, no LDS)
    DECLROW(CW0) DECLROW(CW1) DECLROW(CW2) DECLROW(CW3)
    LOADROW(CW0, wsWhh + (0*NH + kc)*52)
    LOADROW(CW1, wsWhh + (1*NH + kc)*52)
    LOADROW(CW2, wsWhh + (2*NH + kc)*52)
    LOADROW(CW3, wsWhh + (3*NH + kc)*52)
    asm volatile("s_waitcnt vmcnt(0)" ::: "memory");
    __builtin_amdgcn_sched_barrier(0);

    // xp: 4-deep compiler-visible rotation (no barriers exist to drain it)
    const float* xpb = xp + (size_t)b * tcAlloc * 200 + 4 * kc;
    f32x4 xq0 = *(const f32x4*)&xpb[0];
    f32x4 xq1 = *(const f32x4*)&xpb[200];
    f32x4 xq2 = *(const f32x4*)&xpb[400];
    f32x4 xq3 = *(const f32x4*)&xpb[600];
    float hkeep = 0.f;

    for (int s4 = 0; s4 < nsteps; s4 += 4) {
        SSTEP(xq0, s4 + 0)
        SSTEP(xq1, s4 + 1)
        SSTEP(xq2, s4 + 2)
        SSTEP(xq3, s4 + 3)
    }

    if (kln < NH) {
        stH[b * NH + kln] = hv;
        stC[b * NH + kln] = cst;
        if (lastidx >= t0 && lastidx < t1) lastH[b * NH + kln] = hkeep;
    }
}

// ---------------- K3: pooling + concat + linear (unchanged — proven) ---------------------
__global__ __launch_bounds__(256)
void k3_final(const int* __restrict__ x, const int* __restrict__ lengths,
              const float* __restrict__ emb_table,
              const float* __restrict__ W_lin, const float* __restrict__ b_lin,
              const float* __restrict__ lastH, float* __restrict__ out)
{
    const int b = blockIdx.x, tid = threadIdx.x;
    __shared__ int xv[NT];
    __shared__ float ps[5][52], pm[5][52];
    __shared__ float rep[160];

    for (int i = tid; i < NT; i += 256) xv[i] = x[(size_t)b * NT + i];
    __syncthreads();
    const int g = tid / ND, d = tid - g * ND;
    if (tid < 250) {
        float s = 0.f, m = -INFINITY;
        #pragma unroll 4
        for (int t = g; t < NT; t += 5) {
            float e = emb_table[(size_t)xv[t] * ND + d];
            s += e; m = fmaxf(m, e);
        }
        ps[g][d] = s; pm[g][d] = m;
    }
    __syncthreads();
    if (tid < NH) {
        float s = ps[0][tid] + ps[1][tid] + ps[2][tid] + ps[3][tid] + ps[4][tid];
        float m = fmaxf(fmaxf(fmaxf(pm[0][tid], pm[1][tid]), fmaxf(pm[2][tid], pm[3][tid])), pm[4][tid]);
        rep[tid]          = lastH[b * NH + tid];
        rep[NH + tid]     = s / (float)lengths[b];
        rep[2 * NH + tid] = m;
    }
    __syncthreads();
    if (tid < NC) {
        float acc = b_lin[tid];
        #pragma unroll 5
        for (int j = 0; j < 3 * NH; ++j)
            acc = fmaf(rep[j], W_lin[tid * 3 * NH + j], acc);
        out[(size_t)b * NC + tid] = acc;
    }
}

extern "C" void kernel_launch(void* const* d_in, const int* in_sizes, int n_in,
                              void* d_out, int out_size, void* d_ws, size_t ws_size,
                              hipStream_t stream) {
    const int*   x     = (const int*)d_in[0];
    const int*   len   = (const int*)d_in[1];
    const float* emb   = (const float*)d_in[3];
    const float* W_ih  = (const float*)d_in[4];
    const float* W_hh  = (const float*)d_in[5];
    const float* b_ih  = (const float*)d_in[6];
    const float* b_hh  = (const float*)d_in[7];
    const float* W_lin = (const float*)d_in[8];
    const float* b_lin = (const float*)d_in[9];
    float* outp = (float*)d_out;

    // ws: [stH][stC][lastH] | @160KB: wsWih[200*52], wsWhh[200*52] | @256KB: xp (+8KB slack)
    float* stH   = (float*)d_ws;
    float* stC   = stH + NB * NH;
    float* lastH = stC + NB * NH;
    float* wsWih = (float*)((char*)d_ws + 160 * 1024);
    float* wsWhh = wsWih + 200 * 52;
    const size_t xpOff = 256 * 1024;
    float* xp = (float*)((char*)d_ws + xpOff);

    size_t avail = (ws_size > xpOff + 8192) ? ws_size - xpOff - 8192 : 0;
    int tc = (int)(avail / ((size_t)NB * 200 * sizeof(float)));
    tc &= ~3;                 // chunks are multiples of 4 (NT=512 -> every chunk too)
    if (tc > NT) tc = NT;
    if (tc < 4)  tc = 4;

    hipLaunchKernelGGL(k0_prep, dim3(82), dim3(256), 0, stream, W_hh, W_ih, wsWih, wsWhh);

    for (int t0 = 0; t0 < NT; t0 += tc) {
        const int t1 = min(NT, t0 + tc);
        const int tiles = (t1 - t0 + 63) / 64;
        hipLaunchKernelGGL(k1_xproj, dim3(NB * tiles), dim3(256), 0, stream,
                           x, len, emb, wsWih, b_ih, b_hh, xp, t0, t1, tiles, tc);
        hipLaunchKernelGGL(k2_scan, dim3(NB), dim3(64), 0, stream,
                           len, wsWhh, xp, stH, stC, lastH, t0, t1, tc);
    }
    hipLaunchKernelGGL(k3_final, dim3(NB), dim3(256), 0, stream,
                       x, len, emb, W_lin, b_lin, lastH, outp);
}

// Round 13
// 268.884 us; speedup vs baseline: 1.2243x; 1.2121x over previous
//
#include <hip/hip_runtime.h>
#include <cmath>

#define NB 256   // batch
#define NT 512   // seq len
#define ND 50    // emb dim
#define NH 50    // hidden
#define NC 5     // classes

typedef float f32x4 __attribute__((ext_vector_type(4)));
typedef float f32x2 __attribute__((ext_vector_type(2)));

__device__ __forceinline__ float rcpf(float x) { return __builtin_amdgcn_rcpf(x); }
// readlane: uniform result -> SGPR; lane index compile-time const
__device__ __forceinline__ float rdl(float v, int l) {
    return __int_as_float(__builtin_amdgcn_readlane(__float_as_int(v), l));
}
// asm loads: non-rematerializable. ONLY on 16B-aligned addresses (52-float padded rows).
__device__ __forceinline__ void gload4(f32x4& d, const float* p) {
    asm volatile("global_load_dwordx4 %0, %1, off" : "=v"(d) : "v"(p));
}

#define FENCE_BAR                                             \
    asm volatile("s_waitcnt lgkmcnt(0)" ::: "memory");        \
    __builtin_amdgcn_s_barrier();                             \
    asm volatile("" ::: "memory");

// ---------------- K0: repack weights into padded [200][52] rows (16B-aligned) ------------
__global__ __launch_bounds__(256)
void k0_prep(const float* __restrict__ W_hh, const float* __restrict__ W_ih,
             float* __restrict__ wsWih, float* __restrict__ wsWhh)
{
    int idx = blockIdx.x * 256 + threadIdx.x;
    if (idx < 200 * 52) {
        int d = idx / 52, c = idx - (idx / 52) * 52;
        wsWih[idx] = (c < ND) ? W_ih[d * ND + c] : 0.f;
    } else if (idx < 2 * 200 * 52) {
        int j = idx - 200 * 52;
        int d = j / 52, c = j - (j / 52) * 52;
        wsWhh[j] = (c < NH) ? W_hh[d * NH + c] : 0.f;
    }
}

#define DECLROW(P) f32x4 P##_0{},P##_1{},P##_2{},P##_3{},P##_4{},P##_5{},P##_6{},P##_7{}, \
                         P##_8{},P##_9{},P##_10{},P##_11{},P##_12{};
#define LOADROW(P,B) { const float* b_=(B); \
    gload4(P##_0,b_+0);  gload4(P##_1,b_+4);  gload4(P##_2,b_+8);  gload4(P##_3,b_+12); \
    gload4(P##_4,b_+16); gload4(P##_5,b_+20); gload4(P##_6,b_+24); gload4(P##_7,b_+28); \
    gload4(P##_8,b_+32); gload4(P##_9,b_+36); gload4(P##_10,b_+40); gload4(P##_11,b_+44); \
    gload4(P##_12,b_+48); }

// k1 dot: gold order (13 tuples over the zero-padded row; pads are exact no-ops)
#define DOTI(J, HP) { f32x4 h4 = (HP)[J];                          \
    a0 = fmaf(h4.x, w##J.x, a0); a1 = fmaf(h4.y, w##J.y, a1);     \
    a2 = fmaf(h4.z, w##J.z, a2); a3 = fmaf(h4.w, w##J.w, a3); }
#define DOTI13(HP) DOTI(0,HP) DOTI(1,HP) DOTI(2,HP) DOTI(3,HP) DOTI(4,HP) DOTI(5,HP) \
    DOTI(6,HP) DOTI(7,HP) DOTI(8,HP) DOTI(9,HP) DOTI(10,HP) DOTI(11,HP) DOTI(12,HP)

// ---------------- K1: xp[b,t,4u+g] = W_ih[g*50+u] . emb[x[b,t]] + b_ih + b_hh ------------
// (verbatim proven structure from rounds 5/7/10/11/12)
__global__ __launch_bounds__(256)
void k1_xproj(const int* __restrict__ x, const int* __restrict__ lengths,
              const float* __restrict__ emb_table,
              const float* __restrict__ wsWih, const float* __restrict__ b_ih,
              const float* __restrict__ b_hh,
              float* __restrict__ xp, int t0, int t1, int tiles, int tcAlloc)
{
    const int b    = blockIdx.x / tiles;
    const int tile = blockIdx.x % tiles;
    const int rt0  = t0 + tile * 64;
    if (rt0 >= t1) return;
    if (rt0 >= lengths[b]) return;            // rows past length are never consumed
    const int nrows = min(64, t1 - rt0);

    __shared__ int xv[64];
    __shared__ __align__(16) float eL[64][52];

    const int tid = threadIdx.x;

    float bsum = 0.f;
    const float* wrow = wsWih + tid * 52;
    f32x4 w0{},w1{},w2{},w3{},w4{},w5{},w6{},w7{},w8{},w9{},w10{},w11{},w12{};
    gload4(w0,wrow+0); gload4(w1,wrow+4); gload4(w2,wrow+8); gload4(w3,wrow+12);
    gload4(w4,wrow+16); gload4(w5,wrow+20); gload4(w6,wrow+24); gload4(w7,wrow+28);
    gload4(w8,wrow+32); gload4(w9,wrow+36); gload4(w10,wrow+40); gload4(w11,wrow+44);
    gload4(w12,wrow+48);
    if (tid < 200) bsum = b_ih[tid] + b_hh[tid];
    if (tid < nrows) xv[tid] = x[(size_t)b * NT + rt0 + tid];
    __syncthreads();
    for (int idx = tid; idx < nrows * 52; idx += 256) {
        int row = idx / 52, col = idx - row * 52;
        eL[row][col] = (col < ND) ? emb_table[(size_t)xv[row] * ND + col] : 0.f;
    }
    asm volatile("s_waitcnt vmcnt(0)" ::: "memory");  // weights resident
    __builtin_amdgcn_sched_barrier(0);
    __syncthreads();
    if (tid < 200) {
        const int wr = 4 * (tid % NH) + (tid / NH);   // quad-permuted position
        float* xpb = xp + ((size_t)b * tcAlloc + (rt0 - t0)) * 200 + wr;
        for (int row = 0; row < nrows; ++row) {
            const f32x4* ep = (const f32x4*)&eL[row][0];
            float a0 = bsum, a1 = 0.f, a2 = 0.f, a3 = 0.f;
            DOTI13(ep)
            xpb[(size_t)row * 200] = (a0 + a1) + (a2 + a3);
        }
    }
}

// ---------------- K2: 4 waves x 1 gate/lane — weights fit UNDER the ~128-VGPR cap --------
// gate dot, bitwise-gold (== R12's absmax-0.0 CDOT): A01=(a0,a1) over j%4∈{0,1},
// A23=(a2,a3) over j%4∈{2,3}, tails h48->a2/h49->a3, combine (a0+a1)+(a2+a3).
#define FMA2(H,W,A) __builtin_elementwise_fma((H),(W),(A))
#define CDOT1(SEED,OUT) { f32x2 A01 = {(SEED), 0.f}, A23 = {0.f, 0.f};        \
    A01=FMA2(hp0 ,CW_0.xy ,A01); A23=FMA2(hp1 ,CW_0.zw ,A23);                 \
    A01=FMA2(hp2 ,CW_1.xy ,A01); A23=FMA2(hp3 ,CW_1.zw ,A23);                 \
    A01=FMA2(hp4 ,CW_2.xy ,A01); A23=FMA2(hp5 ,CW_2.zw ,A23);                 \
    A01=FMA2(hp6 ,CW_3.xy ,A01); A23=FMA2(hp7 ,CW_3.zw ,A23);                 \
    A01=FMA2(hp8 ,CW_4.xy ,A01); A23=FMA2(hp9 ,CW_4.zw ,A23);                 \
    A01=FMA2(hp10,CW_5.xy ,A01); A23=FMA2(hp11,CW_5.zw ,A23);                 \
    A01=FMA2(hp12,CW_6.xy ,A01); A23=FMA2(hp13,CW_6.zw ,A23);                 \
    A01=FMA2(hp14,CW_7.xy ,A01); A23=FMA2(hp15,CW_7.zw ,A23);                 \
    A01=FMA2(hp16,CW_8.xy ,A01); A23=FMA2(hp17,CW_8.zw ,A23);                 \
    A01=FMA2(hp18,CW_9.xy ,A01); A23=FMA2(hp19,CW_9.zw ,A23);                 \
    A01=FMA2(hp20,CW_10.xy,A01); A23=FMA2(hp21,CW_10.zw,A23);                 \
    A01=FMA2(hp22,CW_11.xy,A01); A23=FMA2(hp23,CW_11.zw,A23);                 \
    A23=FMA2(hp24,CW_12.xy,A23);                                              \
    OUT = (A01.x + A01.y) + (A23.x + A23.y); }

// One step. Uniform control flow for ALL 256 threads (barrier legality).
// acts double-buffered by step parity: write(s+1) never races read(s).
#define SSTEP(XQ, S) {                                                        \
    f32x2 hp0 ={rdl(hv,0 ),rdl(hv,1 )}, hp1 ={rdl(hv,2 ),rdl(hv,3 )};         \
    f32x2 hp2 ={rdl(hv,4 ),rdl(hv,5 )}, hp3 ={rdl(hv,6 ),rdl(hv,7 )};         \
    f32x2 hp4 ={rdl(hv,8 ),rdl(hv,9 )}, hp5 ={rdl(hv,10),rdl(hv,11)};         \
    f32x2 hp6 ={rdl(hv,12),rdl(hv,13)}, hp7 ={rdl(hv,14),rdl(hv,15)};         \
    f32x2 hp8 ={rdl(hv,16),rdl(hv,17)}, hp9 ={rdl(hv,18),rdl(hv,19)};         \
    f32x2 hp10={rdl(hv,20),rdl(hv,21)}, hp11={rdl(hv,22),rdl(hv,23)};         \
    f32x2 hp12={rdl(hv,24),rdl(hv,25)}, hp13={rdl(hv,26),rdl(hv,27)};         \
    f32x2 hp14={rdl(hv,28),rdl(hv,29)}, hp15={rdl(hv,30),rdl(hv,31)};         \
    f32x2 hp16={rdl(hv,32),rdl(hv,33)}, hp17={rdl(hv,34),rdl(hv,35)};         \
    f32x2 hp18={rdl(hv,36),rdl(hv,37)}, hp19={rdl(hv,38),rdl(hv,39)};         \
    f32x2 hp20={rdl(hv,40),rdl(hv,41)}, hp21={rdl(hv,42),rdl(hv,43)};         \
    f32x2 hp22={rdl(hv,44),rdl(hv,45)}, hp23={rdl(hv,46),rdl(hv,47)};         \
    f32x2 hp24={rdl(hv,48),rdl(hv,49)};                                       \
    float gg;                                                                 \
    CDOT1(XQ, gg)                                                             \
    { int sn_ = (S) + 4; if (sn_ > nsteps - 1) sn_ = nsteps - 1;              \
      XQ = xpb[(size_t)sn_ * 200]; }                                          \
    float act = fmaf(rcpf(1.f + __expf(-sce * gg)), sce, ade);                \
    abuf[(S) & 1][wid][kln] = act;                                            \
    FENCE_BAR                                                                 \
    float i_ = abuf[(S) & 1][0][kln];                                         \
    float f_ = abuf[(S) & 1][1][kln];                                         \
    float gt = abuf[(S) & 1][2][kln];                                         \
    float o_ = abuf[(S) & 1][3][kln];                                         \
    cst = fmaf(f_, cst, i_ * gt);                                             \
    float th = fmaf(rcpf(1.f + __expf(-2.f * cst)), 2.f, -1.f);               \
    hv = o_ * th;                                                             \
    hkeep = (t0 + (S) == lastidx) ? hv : hkeep;                               \
}

__global__ __launch_bounds__(256)
__attribute__((amdgpu_waves_per_eu(1, 1)))   // 4 waves -> 1 per SIMD, full budgets
void k2_scan(const int* __restrict__ lengths, const float* __restrict__ wsWhh,
             const float* __restrict__ xp,
             float* __restrict__ stH, float* __restrict__ stC, float* __restrict__ lastH,
             int t0, int t1, int tcAlloc)
{
    const int b   = blockIdx.x, tid = threadIdx.x;
    const int wid = tid >> 6;                  // gate q: 0=i 1=f 2=g 3=o
    const int kln = tid & 63;                  // lane = hidden unit
    const int kc  = (kln < NH) ? kln : NH - 1; // lanes 50-63 shadow unit 49 (harmless dup)

    __shared__ __align__(16) float abuf[2][4][64];  // [parity][gate][lane] acts, 2KB

    const int lastidx = min(lengths[b], NT) - 1;
    const int nsteps  = t1 - t0;

    // all 4 waves hold identical (hv, cst) per lane -> h broadcast stays in-wave (readlane)
    float hv  = (t0 == 0) ? 0.f : stH[b * NH + kc];
    float cst = (t0 == 0) ? 0.f : stC[b * NH + kc];

    // weights: ONE gate row = 13 aligned dwordx4 = 52 VGPRs (fits under the ~128 cap)
    DECLROW(CW)
    LOADROW(CW, wsWhh + ((size_t)wid * NH + kc) * 52)
    asm volatile("s_waitcnt vmcnt(0)" ::: "memory");
    __builtin_amdgcn_sched_barrier(0);

    const float sce = (wid == 2) ? 2.f : 1.f;      // gate g: tanh(x)=2*sigmoid(2x)-1
    const float ade = (wid == 2) ? -1.f : 0.f;     // sigmoid: fma(r,1,0)==r bitwise

    // xq: one float per step (quad-permuted slot 4k+q), 4-deep compiler rotation
    const float* xpb = xp + (size_t)b * tcAlloc * 200 + 4 * kc + wid;
    float xq0 = xpb[0];
    float xq1 = xpb[200];
    float xq2 = xpb[400];
    float xq3 = xpb[600];
    float hkeep = 0.f;

    for (int s4 = 0; s4 < nsteps; s4 += 4) {
        SSTEP(xq0, s4 + 0)
        SSTEP(xq1, s4 + 1)
        SSTEP(xq2, s4 + 2)
        SSTEP(xq3, s4 + 3)
    }

    if (wid == 0 && kln < NH) {
        stH[b * NH + kln] = hv;
        stC[b * NH + kln] = cst;
        if (lastidx >= t0 && lastidx < t1) lastH[b * NH + kln] = hkeep;
    }
}

// ---------------- K3: pooling + concat + linear (unchanged — proven) ---------------------
__global__ __launch_bounds__(256)
void k3_final(const int* __restrict__ x, const int* __restrict__ lengths,
              const float* __restrict__ emb_table,
              const float* __restrict__ W_lin, const float* __restrict__ b_lin,
              const float* __restrict__ lastH, float* __restrict__ out)
{
    const int b = blockIdx.x, tid = threadIdx.x;
    __shared__ int xv[NT];
    __shared__ float ps[5][52], pm[5][52];
    __shared__ float rep[160];

    for (int i = tid; i < NT; i += 256) xv[i] = x[(size_t)b * NT + i];
    __syncthreads();
    const int g = tid / ND, d = tid - g * ND;
    if (tid < 250) {
        float s = 0.f, m = -INFINITY;
        #pragma unroll 4
        for (int t = g; t < NT; t += 5) {
            float e = emb_table[(size_t)xv[t] * ND + d];
            s += e; m = fmaxf(m, e);
        }
        ps[g][d] = s; pm[g][d] = m;
    }
    __syncthreads();
    if (tid < NH) {
        float s = ps[0][tid] + ps[1][tid] + ps[2][tid] + ps[3][tid] + ps[4][tid];
        float m = fmaxf(fmaxf(fmaxf(pm[0][tid], pm[1][tid]), fmaxf(pm[2][tid], pm[3][tid])), pm[4][tid]);
        rep[tid]          = lastH[b * NH + tid];
        rep[NH + tid]     = s / (float)lengths[b];
        rep[2 * NH + tid] = m;
    }
    __syncthreads();
    if (tid < NC) {
        float acc = b_lin[tid];
        #pragma unroll 5
        for (int j = 0; j < 3 * NH; ++j)
            acc = fmaf(rep[j], W_lin[tid * 3 * NH + j], acc);
        out[(size_t)b * NC + tid] = acc;
    }
}

extern "C" void kernel_launch(void* const* d_in, const int* in_sizes, int n_in,
                              void* d_out, int out_size, void* d_ws, size_t ws_size,
                              hipStream_t stream) {
    const int*   x     = (const int*)d_in[0];
    const int*   len   = (const int*)d_in[1];
    const float* emb   = (const float*)d_in[3];
    const float* W_ih  = (const float*)d_in[4];
    const float* W_hh  = (const float*)d_in[5];
    const float* b_ih  = (const float*)d_in[6];
    const float* b_hh  = (const float*)d_in[7];
    const float* W_lin = (const float*)d_in[8];
    const float* b_lin = (const float*)d_in[9];
    float* outp = (float*)d_out;

    // ws: [stH][stC][lastH] | @160KB: wsWih[200*52], wsWhh[200*52] | @256KB: xp (+8KB slack)
    float* stH   = (float*)d_ws;
    float* stC   = stH + NB * NH;
    float* lastH = stC + NB * NH;
    float* wsWih = (float*)((char*)d_ws + 160 * 1024);
    float* wsWhh = wsWih + 200 * 52;
    const size_t xpOff = 256 * 1024;
    float* xp = (float*)((char*)d_ws + xpOff);

    size_t avail = (ws_size > xpOff + 8192) ? ws_size - xpOff - 8192 : 0;
    int tc = (int)(avail / ((size_t)NB * 200 * sizeof(float)));
    tc &= ~3;                 // chunks are multiples of 4 (NT=512 -> every chunk too)
    if (tc > NT) tc = NT;
    if (tc < 4)  tc = 4;

    hipLaunchKernelGGL(k0_prep, dim3(82), dim3(256), 0, stream, W_hh, W_ih, wsWih, wsWhh);

    for (int t0 = 0; t0 < NT; t0 += tc) {
        const int t1 = min(NT, t0 + tc);
        const int tiles = (t1 - t0 + 63) / 64;
        hipLaunchKernelGGL(k1_xproj, dim3(NB * tiles), dim3(256), 0, stream,
                           x, len, emb, wsWih, b_ih, b_hh, xp, t0, t1, tiles, tc);
        hipLaunchKernelGGL(k2_scan, dim3(NB), dim3(256), 0, stream,
                           len, wsWhh, xp, stH, stC, lastH, t0, t1, tc);
    }
    hipLaunchKernelGGL(k3_final, dim3(NB), dim3(256), 0, stream,
                       x, len, emb, W_lin, b_lin, lastH, outp);
}